// Round 1
// baseline (480.740 us; speedup 1.0000x reference)
//
#include <hip/hip_runtime.h>
#include <math.h>

// Problem constants (from reference)
constexpr int N = 50000;
constexpr int E = 800000;
constexpr int D = 32;     // layer dim
constexpr int R = 20;     // relations
constexpr int B = 4;      // bases

// ---------------------------------------------------------------------------
// x0 = concat(feat[N,16], embed[idx][N,16])  -> x [N,32]
__global__ void build_x0(const float* __restrict__ feat,
                         const float* __restrict__ embed,
                         const int* __restrict__ idx,
                         float* __restrict__ x) {
    int t = blockIdx.x * blockDim.x + threadIdx.x;
    if (t >= N * D) return;
    int n = t >> 5, j = t & 31;
    float v;
    if (j < 16) v = feat[n * 16 + j];
    else        v = embed[idx[n] * 16 + (j - 16)];
    x[t] = v;
}

// ---------------------------------------------------------------------------
// Per-layer tiny precompute:
//   W[r]     = sum_b wcomp[r,b] * bases[b]          [R, D, D]
//   attnA[r] = attn_tab[r] @ Aw[64:96] + Ab         [R, D]
// grid = R blocks, 32 threads each (lane j = output col)
__global__ void prep_layer(const float* __restrict__ bases,
                           const float* __restrict__ wcomp,
                           const float* __restrict__ attn_tab,
                           const float* __restrict__ Aw,
                           const float* __restrict__ Ab,
                           float* __restrict__ W,
                           float* __restrict__ attnA) {
    int r = blockIdx.x;
    int j = threadIdx.x;  // 0..31
    float w0 = wcomp[r * B + 0], w1 = wcomp[r * B + 1];
    float w2 = wcomp[r * B + 2], w3 = wcomp[r * B + 3];
    for (int i = 0; i < D; ++i) {
        int o = i * D + j;
        W[r * D * D + o] = w0 * bases[0 * D * D + o] + w1 * bases[1 * D * D + o]
                         + w2 * bases[2 * D * D + o] + w3 * bases[3 * D * D + o];
    }
    float acc = Ab[j];
    for (int k = 0; k < 32; ++k)
        acc = fmaf(attn_tab[r * 32 + k], Aw[(64 + k) * D + j], acc);
    attnA[r * D + j] = acc;
}

// ---------------------------------------------------------------------------
// Node stage (per layer): for each node n
//   sA[n]   = x[n] @ Aw[0:32]      (src half of attention pre-MLP)
//   dA[n]   = x[n] @ Aw[32:64]     (dst half)
//   curr[n] = x[n] @ selfw
//   nei[n]  = 0
// 32 lanes per node, lane j = output col; __shfl broadcasts x[i].
__global__ void node_stage(const float* __restrict__ x,
                           const float* __restrict__ Aw,
                           const float* __restrict__ selfw,
                           float* __restrict__ sA,
                           float* __restrict__ dA,
                           float* __restrict__ curr,
                           float* __restrict__ nei) {
    int t = blockIdx.x * blockDim.x + threadIdx.x;
    int n = t >> 5, j = t & 31;
    if (n >= N) return;
    float xv = x[n * D + j];
    float sa = 0.f, da = 0.f, cu = 0.f;
#pragma unroll
    for (int i = 0; i < D; ++i) {
        float xi = __shfl(xv, i, 32);
        sa = fmaf(xi, Aw[i * D + j], sa);
        da = fmaf(xi, Aw[(D + i) * D + j], da);
        cu = fmaf(xi, selfw[i * D + j], cu);
    }
    sA[n * D + j] = sa;
    dA[n * D + j] = da;
    curr[n * D + j] = cu;
    nei[n * D + j] = 0.f;
}

// ---------------------------------------------------------------------------
// Edge stage: 32 lanes per edge, lane j = output col.
//   msg  = x[src] @ W[etype]
//   hid  = relu(sA[src] + dA[dst] + attnA[etype])     (e_in@Aw+Ab factorized)
//   a    = sigmoid(dot(hid, Bw) + Bb)
//   nei[dst] += a * msg   (atomic)
__global__ void edge_stage(const float* __restrict__ x,
                           const float* __restrict__ sA,
                           const float* __restrict__ dA,
                           const float* __restrict__ attnA,
                           const float* __restrict__ W,
                           const float* __restrict__ Bw,
                           const float* __restrict__ Bb,
                           const int* __restrict__ src,
                           const int* __restrict__ dst,
                           const int* __restrict__ etype,
                           float* __restrict__ nei) {
    int t = blockIdx.x * blockDim.x + threadIdx.x;
    int e = t >> 5, j = t & 31;
    if (e >= E) return;
    int s = src[e], d = dst[e], r = etype[e];

    float xv = x[s * D + j];
    const float* Wr = W + r * D * D;
    float m = 0.f;
#pragma unroll
    for (int i = 0; i < D; ++i)
        m = fmaf(__shfl(xv, i, 32), Wr[i * D + j], m);

    float h = sA[s * D + j] + dA[d * D + j] + attnA[r * D + j];
    h = fmaxf(h, 0.f);

    float p = h * Bw[j];
#pragma unroll
    for (int off = 16; off > 0; off >>= 1)
        p += __shfl_xor(p, off, 32);
    float score = 1.f / (1.f + __expf(-(p + Bb[0])));

    atomicAdd(&nei[d * D + j], score * m);
}

// ---------------------------------------------------------------------------
// h = relu(nei + curr)
__global__ void finalize(const float* __restrict__ nei,
                         const float* __restrict__ curr,
                         float* __restrict__ out) {
    int t = blockIdx.x * blockDim.x + threadIdx.x;
    if (t >= N * D) return;
    out[t] = fmaxf(nei[t] + curr[t], 0.f);
}

// ---------------------------------------------------------------------------
extern "C" void kernel_launch(void* const* d_in, const int* in_sizes, int n_in,
                              void* d_out, int out_size, void* d_ws, size_t ws_size,
                              hipStream_t stream) {
    const float* feat  = (const float*)d_in[0];
    const float* embed = (const float*)d_in[1];
    const float* attn  = (const float*)d_in[2];
    const int*   idx   = (const int*)d_in[3];
    const int*   src   = (const int*)d_in[4];
    const int*   dst   = (const int*)d_in[5];
    const int*   ety   = (const int*)d_in[6];
    const float* bases[2] = {(const float*)d_in[7],  (const float*)d_in[14]};
    const float* wcomp[2] = {(const float*)d_in[8],  (const float*)d_in[15]};
    const float* selfw[2] = {(const float*)d_in[9],  (const float*)d_in[16]};
    const float* Aw[2]    = {(const float*)d_in[10], (const float*)d_in[17]};
    const float* Ab[2]    = {(const float*)d_in[11], (const float*)d_in[18]};
    const float* Bw[2]    = {(const float*)d_in[12], (const float*)d_in[19]};
    const float* Bb[2]    = {(const float*)d_in[13], (const float*)d_in[20]};
    float* out = (float*)d_out;

    // workspace layout (floats): 5*N*D + R*D*D + R*D  ~= 32.1 MB
    float* ws    = (float*)d_ws;
    float* x     = ws;                 // N*D
    float* sA    = x + (size_t)N * D;  // N*D
    float* dA    = sA + (size_t)N * D; // N*D
    float* curr  = dA + (size_t)N * D; // N*D
    float* nei   = curr + (size_t)N * D; // N*D
    float* W     = nei + (size_t)N * D;  // R*D*D
    float* attnA = W + R * D * D;        // R*D

    dim3 blk(256);
    int gx = (N * D + 255) / 256;      // 6250 blocks, 32 lanes/node
    int ge = (E * 32 + 255) / 256;     // 100000 blocks, 32 lanes/edge

    build_x0<<<gx, blk, 0, stream>>>(feat, embed, idx, x);

    for (int l = 0; l < 2; ++l) {
        prep_layer<<<R, 32, 0, stream>>>(bases[l], wcomp[l], attn, Aw[l], Ab[l],
                                         W, attnA);
        node_stage<<<gx, blk, 0, stream>>>(x, Aw[l], selfw[l], sA, dA, curr, nei);
        edge_stage<<<ge, blk, 0, stream>>>(x, sA, dA, attnA, W, Bw[l], Bb[l],
                                           src, dst, ety, nei);
        finalize<<<gx, blk, 0, stream>>>(nei, curr, (l == 0) ? x : out);
    }
}